// Round 8
// baseline (5305.044 us; speedup 1.0000x reference)
//
#include <hip/hip_runtime.h>

// Hartree-Fock SCF, NX=240, A_ORB=2, 500 sequential iterations.
// Single persistent workgroup (512 thr = 8 waves, 1 CU), state in LDS.
// Toeplitz kin/Vint -> matvecs are length-240 convolutions with per-thread
// register-resident coefficient windows (loaded once, reused 500 iters).
// R3: DPP reductions; conv split K-waves/V-waves over j-chunks.
// R4: Gram-Schmidt collapsed to ONE batched 6-way DPP reduction.
// R5/R6: Vint convolutions in f16 via v_dot2_f32_f16 (fp32 accum); kin
//   stays fp32 (oscillatory kernel). Packed-pair X arrays; j-chunks
//   {64,64,64,48}.
// R7: fix spill regression — ONE shared register window win[68] (K-waves:
//   17 bitcast fp32 quads; V-waves: 66 packed f16 pairs) instead of two
//   separately-live arrays (134 regs -> scratch spill at the 128 cap), and
//   __launch_bounds__(NTH,1) for VGPR headroom.

#define NXX  240
#define NPAD 256
#define NTH  512

typedef _Float16 h2 __attribute__((ext_vector_type(2)));

__device__ __forceinline__ h2 bch2(unsigned u) { union { unsigned u; h2 h; } c; c.u = u; return c.h; }
__device__ __forceinline__ unsigned bcu(h2 h)  { union { unsigned u; h2 h; } c; c.h = h; return c.u; }
__device__ __forceinline__ unsigned pkh(float a, float b) {
  h2 p; p.x = (_Float16)a; p.y = (_Float16)b; return bcu(p);
}

__device__ __forceinline__ float fdot2(h2 a, h2 b, float c) {
#if __has_builtin(__builtin_amdgcn_fdot2)
  return __builtin_amdgcn_fdot2(a, b, c, false);
#else
  float d;
  asm("v_dot2_f32_f16 %0, %1, %2, %3" : "=v"(d) : "v"(a), "v"(b), "v"(c));
  return d;
#endif
}

// ---- wave64 all-reduce via DPP, N interleaved chains; result broadcast ----
template <int CTRL, int N>
__device__ __forceinline__ void dppStepN(float (&v)[N]) {
#pragma unroll
  for (int k = 0; k < N; ++k) {
    int s = __builtin_amdgcn_update_dpp(0, __float_as_int(v[k]), CTRL, 0xF, 0xF, false);
    v[k] += __int_as_float(s);
  }
}
template <int N>
__device__ __forceinline__ void waveSumDppN(float (&v)[N]) {
  dppStepN<0xB1>(v);   // quad_perm xor1
  dppStepN<0x4E>(v);   // quad_perm xor2
  dppStepN<0x141>(v);  // row_half_mirror (xor 7)
  dppStepN<0x140>(v);  // row_mirror (xor 15)
  dppStepN<0x142>(v);  // row_bcast:15
  dppStepN<0x143>(v);  // row_bcast:31
#pragma unroll
  for (int k = 0; k < N; ++k)
    v[k] = __int_as_float(__builtin_amdgcn_readlane(__float_as_int(v[k]), 63));
}

struct __align__(16) Smem {
  float cK[512];            // Toeplitz coeffs of kin, index d+256 (zero-padded)
  unsigned pkV[512];        // packed f16 pairs (cV[a], cV[a-1]) at index a
  float uho[NPAD];
  float wfb[2][2][NPAD];    // ping-pong wavefunctions (fp32)
  unsigned xpk[3][NPAD/2];  // packed f16 pairs of p00, p01, p11
  unsigned xprk[4][NPAD/2]; // final-iter packed products wf_m * new_n
  float part[4][6][NPAD];   // conv partials per j-group
};

// K conv: 2 fp32 convs (kin kernel, oscillatory -> needs fp32)
// win holds 17 bitcast fp32 quads; block b uses quads 16-b (hi), 15-b (lo)
template <int NB>
__device__ __forceinline__ void kinConv(const float* x0p, const float* x1p, int jg,
                                        const unsigned* win, float (&a0)[4], float (&a1)[4]) {
#pragma unroll
  for (int b = 0; b < NB; ++b) {
    const int j0 = jg + 4 * b;
    const float4 x0 = *(const float4*)&x0p[j0];
    const float4 x1 = *(const float4*)&x1p[j0];
    float ck[8];
#pragma unroll
    for (int c = 0; c < 4; ++c) {
      ck[c]     = __uint_as_float(win[4 * (15 - b) + c]);
      ck[4 + c] = __uint_as_float(win[4 * (16 - b) + c]);
    }
    const float xs0[4] = {x0.x, x0.y, x0.z, x0.w};
    const float xs1[4] = {x1.x, x1.y, x1.z, x1.w};
#pragma unroll
    for (int s = 0; s < 4; ++s)
#pragma unroll
      for (int r = 0; r < 4; ++r) {
        const int c = 4 + r - s;
        a0[r] = fmaf(xs0[s], ck[c], a0[r]);
        a1[r] = fmaf(xs1[s], ck[c], a1[r]);
      }
  }
}

// V conv: 3 f16 dot2 convs over packed pairs; superblock = 8 j = 4 pairs
template <int NSB>
__device__ __forceinline__ void vConv3(const unsigned* q0, const unsigned* q1,
                                       const unsigned* q2, int jg,
                                       const unsigned* win, float (&A)[3][4]) {
#pragma unroll
  for (int sb = 0; sb < NSB; ++sb) {
    const int base = jg / 2 + 4 * sb;
    const uint4 X0 = *(const uint4*)&q0[base];
    const uint4 X1 = *(const uint4*)&q1[base];
    const uint4 X2 = *(const uint4*)&q2[base];
    const unsigned xs0[4] = {X0.x, X0.y, X0.z, X0.w};
    const unsigned xs1[4] = {X1.x, X1.y, X1.z, X1.w};
    const unsigned xs2[4] = {X2.x, X2.y, X2.z, X2.w};
#pragma unroll
    for (int p = 0; p < 4; ++p)
#pragma unroll
      for (int r = 0; r < 4; ++r) {
        const int tt = r - 2 * p - 8 * sb + (NSB * 8 - 2);   // compile-time
        const h2 c = bch2(win[tt]);
        A[0][r] = fdot2(c, bch2(xs0[p]), A[0][r]);
        A[1][r] = fdot2(c, bch2(xs1[p]), A[1][r]);
        A[2][r] = fdot2(c, bch2(xs2[p]), A[2][r]);
      }
  }
}

// final-iter: 4 f16 product convs
template <int NSB>
__device__ __forceinline__ void vConv4(const unsigned (*q)[NPAD / 2], int jg,
                                       const unsigned* win, float (&A)[4][4]) {
#pragma unroll
  for (int sb = 0; sb < NSB; ++sb) {
    const int base = jg / 2 + 4 * sb;
    const uint4 X0 = *(const uint4*)&q[0][base];
    const uint4 X1 = *(const uint4*)&q[1][base];
    const uint4 X2 = *(const uint4*)&q[2][base];
    const uint4 X3 = *(const uint4*)&q[3][base];
    const unsigned xs0[4] = {X0.x, X0.y, X0.z, X0.w};
    const unsigned xs1[4] = {X1.x, X1.y, X1.z, X1.w};
    const unsigned xs2[4] = {X2.x, X2.y, X2.z, X2.w};
    const unsigned xs3[4] = {X3.x, X3.y, X3.z, X3.w};
#pragma unroll
    for (int p = 0; p < 4; ++p)
#pragma unroll
      for (int r = 0; r < 4; ++r) {
        const int tt = r - 2 * p - 8 * sb + (NSB * 8 - 2);
        const h2 c = bch2(win[tt]);
        A[0][r] = fdot2(c, bch2(xs0[p]), A[0][r]);
        A[1][r] = fdot2(c, bch2(xs1[p]), A[1][r]);
        A[2][r] = fdot2(c, bch2(xs2[p]), A[2][r]);
        A[3][r] = fdot2(c, bch2(xs3[p]), A[3][r]);
      }
  }
}

__global__ void __launch_bounds__(NTH, 1)
hf_kernel(const float* __restrict__ wfy0,
          const float* __restrict__ kin,
          const float* __restrict__ vnt,
          const float* __restrict__ uho_g,
          const float* __restrict__ delx_p,
          const float* __restrict__ pfac_p,
          const int*   __restrict__ iter_p,
          float* __restrict__ out)
{
  __shared__ Smem sm;
  const int t  = (int)threadIdx.x;
  const int wv = t >> 6;
  const int l  = t & 63;
  const int i0 = 4 * l;              // output quad owned by this lane
  const bool isK = (wv < 4);
  const int g  = isK ? wv : wv - 4;  // j-group 0..3
  const int jg = 64 * g;             // chunk starts; lens {64,64,64,48}
  const int len = (g < 3) ? 64 : 48;
  const float delx = delx_p[0];
  const float pfac = pfac_p[0];
  const int itermax = iter_p[0];

  // ---- setup: Toeplitz coeff tables (kin fp32, Vint packed f16 pairs) ----
  for (int a = t; a < 512; a += NTH) {
    int d = a - 256;                 // d = i - j
    float vk = 0.f;
    if (d >= 0 && d < NXX)      vk = kin[(size_t)d * NXX];
    else if (d < 0 && -d < NXX) vk = kin[-d];
    sm.cK[a] = vk;
    float vh = 0.f, vl = 0.f;
    if (d >= 0 && d < NXX)      vh = vnt[(size_t)d * NXX];
    else if (d < 0 && -d < NXX) vh = vnt[-d];
    int d2 = d - 1;
    if (d2 >= 0 && d2 < NXX)      vl = vnt[(size_t)d2 * NXX];
    else if (d2 < 0 && -d2 < NXX) vl = vnt[-d2];
    sm.pkV[a] = pkh(vh, vl);         // (c[a], c[a-1])
  }
  if (t < NPAD) {
    float u  = (t < NXX) ? uho_g[t]        : 0.f;
    float a0 = (t < NXX) ? wfy0[2 * t]     : 0.f;
    float a1 = (t < NXX) ? wfy0[2 * t + 1] : 0.f;
    sm.uho[t] = u;
    sm.wfb[0][0][t] = a0; sm.wfb[0][1][t] = a1;
    sm.wfb[1][0][t] = 0.f; sm.wfb[1][1][t] = 0.f;
  }
  if (t < NPAD / 2) {                // initial packed p-arrays
    int j0 = 2 * t, j1 = 2 * t + 1;
    float w00 = (j0 < NXX) ? wfy0[2 * j0]     : 0.f;
    float w01 = (j0 < NXX) ? wfy0[2 * j0 + 1] : 0.f;
    float w10 = (j1 < NXX) ? wfy0[2 * j1]     : 0.f;
    float w11 = (j1 < NXX) ? wfy0[2 * j1 + 1] : 0.f;
    sm.xpk[0][t] = pkh(w00 * w00, w10 * w10);
    sm.xpk[1][t] = pkh(w00 * w01, w10 * w11);
    sm.xpk[2][t] = pkh(w01 * w01, w11 * w11);
  }
  __syncthreads();

  // ---- ONE shared persistent register window (68 dwords) ----
  // K-wave: 17 bitcast fp32 quads (qbase = l - 16g + 48)
  // V-wave: 66 packed f16 pairs   (Abase = i0 - jg - (len-2) + 256)
  unsigned win[68];
  if (isK) {
    const int qbase = l - 16 * g + 48;
#pragma unroll
    for (int m = 0; m < 17; ++m) {
      const uint4 q = *(const uint4*)&sm.cK[4 * (qbase + m)];
      win[4 * m + 0] = q.x; win[4 * m + 1] = q.y;
      win[4 * m + 2] = q.z; win[4 * m + 3] = q.w;
    }
  } else {
    const int Abase = i0 - jg - (len - 2) + 256;
#pragma unroll
    for (int m = 0; m < 66; ++m) win[m] = sm.pkV[Abase + m];
    win[66] = 0u; win[67] = 0u;
  }

  int cur = 0;
  for (int it = 0; it < itermax; ++it) {
    const bool last = (it == itermax - 1);
    const float* wf0 = sm.wfb[cur][0];
    const float* wf1 = sm.wfb[cur][1];
    float* nw0 = sm.wfb[cur ^ 1][0];
    float* nw1 = sm.wfb[cur ^ 1][1];

    // ===== conv phase: K: kin@wf0, kin@wf1 (fp32); V: V@p00,p01,p11 (f16) ====
    if (isK) {
      float aK0[4] = {0, 0, 0, 0}, aK1[4] = {0, 0, 0, 0};
      if (g < 3) kinConv<16>(wf0, wf1, jg, win, aK0, aK1);
      else       kinConv<12>(wf0, wf1, jg, win, aK0, aK1);
      *(float4*)&sm.part[g][0][i0] = make_float4(aK0[0], aK0[1], aK0[2], aK0[3]);
      *(float4*)&sm.part[g][1][i0] = make_float4(aK1[0], aK1[1], aK1[2], aK1[3]);
    } else {
      float aV[3][4] = {};
      if (g < 3) vConv3<8>(sm.xpk[0], sm.xpk[1], sm.xpk[2], jg, win, aV);
      else       vConv3<6>(sm.xpk[0], sm.xpk[1], sm.xpk[2], jg, win, aV);
#pragma unroll
      for (int c = 0; c < 3; ++c)
        *(float4*)&sm.part[g][2 + c][i0] =
            make_float4(aV[c][0], aV[c][1], aV[c][2], aV[c][3]);
    }
    __syncthreads();   // B1

    // ===== serial wave-0 vector phase: ONE batched reduction (R4) =====
    float w0[4], w1[4], Ut[4], wff0[4], wff1[4], new0[4], new1[4];
    float spe0 = 0.f, spe1 = 0.f, eho = 0.f;

    if (wv == 0) {
      const bool valid = (l < 60);   // rows i0..i0+3 < 240
      float k0[4]  = {0, 0, 0, 0}, k1[4]  = {0, 0, 0, 0};
      float v00[4] = {0, 0, 0, 0}, v01[4] = {0, 0, 0, 0}, v11[4] = {0, 0, 0, 0};
#pragma unroll
      for (int gg = 0; gg < 4; ++gg) {
        const float4 A0 = *(const float4*)&sm.part[gg][0][i0];
        const float4 A1 = *(const float4*)&sm.part[gg][1][i0];
        const float4 A2 = *(const float4*)&sm.part[gg][2][i0];
        const float4 A3 = *(const float4*)&sm.part[gg][3][i0];
        const float4 A4 = *(const float4*)&sm.part[gg][4][i0];
        k0[0]  += A0.x; k0[1]  += A0.y; k0[2]  += A0.z; k0[3]  += A0.w;
        k1[0]  += A1.x; k1[1]  += A1.y; k1[2]  += A1.z; k1[3]  += A1.w;
        v00[0] += A2.x; v00[1] += A2.y; v00[2] += A2.z; v00[3] += A2.w;
        v01[0] += A3.x; v01[1] += A3.y; v01[2] += A3.z; v01[3] += A3.w;
        v11[0] += A4.x; v11[1] += A4.y; v11[2] += A4.z; v11[3] += A4.w;
      }
      const float4 w0q = *(const float4*)&wf0[i0];
      const float4 w1q = *(const float4*)&wf1[i0];
      const float4 uq  = *(const float4*)&sm.uho[i0];
      w0[0] = w0q.x; w0[1] = w0q.y; w0[2] = w0q.z; w0[3] = w0q.w;
      w1[0] = w1q.x; w1[1] = w1q.y; w1[2] = w1q.z; w1[3] = w1q.w;
      const float uh[4] = {uq.x, uq.y, uq.z, uq.w};

      float wb0[4], wb1[4];
      float red[6] = {0, 0, 0, 0, 0, 0};  // s0, s1, c01, d01, a00, sw0
#pragma unroll
      for (int r = 0; r < 4; ++r) {
        Ut[r]   = delx * (v00[r] + v11[r]) + uh[r];          // Udir + U_HO
        wff0[r] = k0[r] - delx * (w0[r] * v00[r] + w1[r] * v01[r]) + Ut[r] * w0[r];
        wff1[r] = k1[r] - delx * (w0[r] * v01[r] + w1[r] * v11[r]) + Ut[r] * w1[r];
        wb0[r]  = w0[r] - pfac * wff0[r];
        wb1[r]  = w1[r] - pfac * wff1[r];
        if (!valid) { wb0[r] = 0.f; wb1[r] = 0.f; }          // mask pad rows
        red[0] += wb0[r] * wb0[r];
        red[1] += wb1[r] * wb1[r];
        red[2] += wb0[r] * wb1[r];
        red[3] += w0[r]  * wb1[r];
        red[4] += wb0[r] * w0[r];
        red[5] += w0[r]  * w0[r];
      }
      waveSumDppN<6>(red);
      const float rdelx = 1.f / delx;
      const float inv0 = 1.f / sqrtf(red[0] * delx);   // 1/||wb0||
      const float inv1 = 1.f / sqrtf(red[1] * delx);   // 1/||wb1||
      const float dB = delx * inv1 * (0.4f * red[2] * inv0 + 0.6f * red[3]);
      const float e0 = 0.16f * rdelx + 0.48f * red[4] * inv0 + 0.36f * red[5];
      const float sB = rdelx - dB * dB * (2.f * rdelx - e0);
      const float invB = 1.f / (sB * delx);
#pragma unroll
      for (int r = 0; r < 4; ++r) {
        const float wfA  = wb0[r] * inv0;
        const float wfBp = wb1[r] * inv1;
        new0[r] = 0.4f * wfA + 0.6f * w0[r];           // n2A == 1 identity
        const float wfB2 = wfBp - new0[r] * dB;
        new1[r] = 0.4f * wfB2 * invB + 0.6f * w1[r];
      }
      *(float4*)&nw0[i0] = make_float4(new0[0], new0[1], new0[2], new0[3]);
      *(float4*)&nw1[i0] = make_float4(new1[0], new1[1], new1[2], new1[3]);
      // packed f16 p-arrays for next iteration's V convs (pads stay 0)
      *(uint2*)&sm.xpk[0][2 * l] = make_uint2(
          pkh(new0[0] * new0[0], new0[1] * new0[1]),
          pkh(new0[2] * new0[2], new0[3] * new0[3]));
      *(uint2*)&sm.xpk[1][2 * l] = make_uint2(
          pkh(new0[0] * new1[0], new0[1] * new1[1]),
          pkh(new0[2] * new1[2], new0[3] * new1[3]));
      *(uint2*)&sm.xpk[2][2 * l] = make_uint2(
          pkh(new1[0] * new1[0], new1[1] * new1[1]),
          pkh(new1[2] * new1[2], new1[3] * new1[3]));

      if (last) {
        float er[3] = {0, 0, 0};                       // spe0, spe1, eho
#pragma unroll
        for (int r = 0; r < 4; ++r) {
          er[0] += w0[r] * wff0[r];                    // w0=0 on pads
          er[1] += w1[r] * wff1[r];
          er[2] += (w0[r] * w0[r] + w1[r] * w1[r]) * uh[r];
        }
        waveSumDppN<3>(er);
        spe0 = er[0] * delx; spe1 = er[1] * delx; eho = er[2] * delx * 0.5f;
      }
    }
    __syncthreads();   // B2 — next conv may read nw*/xpk safely

    // ===== final iteration: ekin/epot =====
    if (last) {
      // pack products wf_m * new_n as f16 pairs (threads 0..127)
      if (t < NPAD / 2) {
        const float2 o0 = *(const float2*)&wf0[2 * t];
        const float2 o1 = *(const float2*)&wf1[2 * t];
        const float2 n0 = *(const float2*)&nw0[2 * t];
        const float2 n1 = *(const float2*)&nw1[2 * t];
        sm.xprk[0][t] = pkh(o0.x * n0.x, o0.y * n0.y);
        sm.xprk[1][t] = pkh(o1.x * n0.x, o1.y * n0.y);
        sm.xprk[2][t] = pkh(o0.x * n1.x, o0.y * n1.y);
        sm.xprk[3][t] = pkh(o1.x * n1.x, o1.y * n1.y);
      }
      __syncthreads();  // B3 (last iter only)

      if (isK) {
        float bA0[4] = {0, 0, 0, 0}, bA1[4] = {0, 0, 0, 0};
        if (g < 3) kinConv<16>(nw0, nw1, jg, win, bA0, bA1);
        else       kinConv<12>(nw0, nw1, jg, win, bA0, bA1);
        *(float4*)&sm.part[g][0][i0] = make_float4(bA0[0], bA0[1], bA0[2], bA0[3]);
        *(float4*)&sm.part[g][1][i0] = make_float4(bA1[0], bA1[1], bA1[2], bA1[3]);
      } else {
        float bV[4][4] = {};
        if (g < 3) vConv4<8>(sm.xprk, jg, win, bV);
        else       vConv4<6>(sm.xprk, jg, win, bV);
#pragma unroll
        for (int c2 = 0; c2 < 4; ++c2)
          *(float4*)&sm.part[g][2 + c2][i0] =
              make_float4(bV[c2][0], bV[c2][1], bV[c2][2], bV[c2][3]);
      }
      __syncthreads();  // B4

      if (wv == 0) {
        float rd[6][4] = {};
#pragma unroll
        for (int gg = 0; gg < 4; ++gg)
#pragma unroll
          for (int c = 0; c < 6; ++c) {
            const float4 A = *(const float4*)&sm.part[gg][c][i0];
            rd[c][0] += A.x; rd[c][1] += A.y; rd[c][2] += A.z; rd[c][3] += A.w;
          }
        float er[2] = {0, 0};                          // ekin, epot integrands
#pragma unroll
        for (int r = 0; r < 4; ++r) {
          // pads contribute 0: w0=w1=new0=new1=0 there
          const float um0 = -delx * (w0[r] * rd[2][r] + w1[r] * rd[3][r]) + Ut[r] * new0[r];
          const float um1 = -delx * (w0[r] * rd[4][r] + w1[r] * rd[5][r]) + Ut[r] * new1[r];
          er[0] += new0[r] * rd[0][r] + new1[r] * rd[1][r];
          er[1] += new0[r] * um0 + new1[r] * um1;
        }
        waveSumDppN<2>(er);
        const float ekin = er[0] * delx, epot = er[1] * delx;
        if (l == 0) {
          const float esum    = spe0 + spe1;
          const float enerhfp = 0.5f * (esum + ekin) + eho;
          const float epot0hf = epot - 2.f * eho;
          const float enerhf  = esum - 0.5f * epot0hf;
          out[0] = enerhf; out[1] = enerhfp; out[2] = ekin;
          out[3] = eho;    out[4] = epot0hf; out[5] = esum;
        }
      }
    }
    cur ^= 1;
  }
}

extern "C" void kernel_launch(void* const* d_in, const int* in_sizes, int n_in,
                              void* d_out, int out_size, void* d_ws, size_t ws_size,
                              hipStream_t stream) {
  const float* wfy0 = (const float*)d_in[0];
  const float* kin  = (const float*)d_in[1];
  const float* vnt  = (const float*)d_in[2];
  const float* uho  = (const float*)d_in[3];
  const float* delx = (const float*)d_in[4];
  const float* pfac = (const float*)d_in[5];
  const int*   itm  = (const int*)d_in[6];
  hipLaunchKernelGGL(hf_kernel, dim3(1), dim3(NTH), 0, stream,
                     wfy0, kin, vnt, uho, delx, pfac, itm, (float*)d_out);
}

// Round 9
// 1079.386 us; speedup vs baseline: 4.9149x; 4.9149x over previous
//
#include <hip/hip_runtime.h>

// Hartree-Fock SCF, NX=240, A_ORB=2, 500 sequential iterations.
// Single persistent workgroup (512 thr = 8 waves, 1 CU), state in LDS.
// Toeplitz kin/Vint -> matvecs are length-240 convolutions with per-thread
// register-resident coefficient windows (loaded once, reused 500 iters).
// R3: DPP reductions; conv split K-waves/V-waves. R4: Gram-Schmidt collapsed
// to ONE batched 6-way DPP reduction (proven 1227us, VGPR=128, no spill).
// R8: f16 V-convs rebuilt on R4's proven-promotable register shape:
//   ONE quad-typed window float4 winq[17] (68 regs, +4 vs R4) — K-waves
//   store R4-verbatim fp32 quads (chunks of 60); V-waves store packed-f16
//   coefficient pairs loaded as uint4 (V chunks {64,64,64,48}, 4-aligned
//   base). V convs use v_dot2_f32_f16 (fp32 accum); x-side p-arrays stored
//   packed f16 (xpk). launch_bounds(NTH,2) as R4. Kin path fp32, verbatim.

#define NXX  240
#define NPAD 256
#define NTH  512
#define KJCH 60    // K-wave j-chunk (4 chunks cover 240)
#define KNB  15    // KJCH/4

typedef _Float16 h2 __attribute__((ext_vector_type(2)));

__device__ __forceinline__ h2 bch2(unsigned u) { union { unsigned u; h2 h; } c; c.u = u; return c.h; }
__device__ __forceinline__ unsigned bcu(h2 h)  { union { unsigned u; h2 h; } c; c.h = h; return c.u; }
__device__ __forceinline__ unsigned pkh(float a, float b) {
  h2 p; p.x = (_Float16)a; p.y = (_Float16)b; return bcu(p);
}

__device__ __forceinline__ float fdot2(h2 a, h2 b, float c) {
#if __has_builtin(__builtin_amdgcn_fdot2)
  return __builtin_amdgcn_fdot2(a, b, c, false);
#else
  float d;
  asm("v_dot2_f32_f16 %0, %1, %2, %3" : "=v"(d) : "v"(a), "v"(b), "v"(c));
  return d;
#endif
}

// compile-time dword extraction from a float4-typed register array
__device__ __forceinline__ float wdw(const float4* w, int idx) {
  const float4 q = w[idx >> 2];
  const int c = idx & 3;
  return c == 0 ? q.x : (c == 1 ? q.y : (c == 2 ? q.z : q.w));
}

// ---- wave64 all-reduce via DPP, N interleaved chains; result broadcast ----
template <int CTRL, int N>
__device__ __forceinline__ void dppStepN(float (&v)[N]) {
#pragma unroll
  for (int k = 0; k < N; ++k) {
    int s = __builtin_amdgcn_update_dpp(0, __float_as_int(v[k]), CTRL, 0xF, 0xF, false);
    v[k] += __int_as_float(s);
  }
}
template <int N>
__device__ __forceinline__ void waveSumDppN(float (&v)[N]) {
  dppStepN<0xB1>(v);   // quad_perm xor1
  dppStepN<0x4E>(v);   // quad_perm xor2
  dppStepN<0x141>(v);  // row_half_mirror (xor 7)
  dppStepN<0x140>(v);  // row_mirror (xor 15)
  dppStepN<0x142>(v);  // row_bcast:15
  dppStepN<0x143>(v);  // row_bcast:31
#pragma unroll
  for (int k = 0; k < N; ++k)
    v[k] = __int_as_float(__builtin_amdgcn_readlane(__float_as_int(v[k]), 63));
}

struct __align__(16) Smem {
  float cK[512];            // Toeplitz coeffs of kin, index d+256 (zero-padded)
  unsigned pkV[512];        // packed f16 pairs (cV[a], cV[a-1]) at index a
  float uho[NPAD];
  float wfb[2][2][NPAD];    // ping-pong wavefunctions (fp32)
  unsigned xpk[3][NPAD/2];  // packed f16 pairs of p00, p01, p11
  unsigned xprk[4][NPAD/2]; // final-iter packed products wf_m * new_n
  float part[4][6][NPAD];   // conv partials per j-group
};

// K conv: 2 fp32 convs, R4-verbatim math. win quads 15-b (hi), 14-b (lo).
__device__ __forceinline__ void kinConv(const float* x0p, const float* x1p, int jg,
                                        const float4* cw, float (&a0)[4], float (&a1)[4]) {
#pragma unroll
  for (int b = 0; b < KNB; ++b) {
    const int j0 = jg + 4 * b;
    const float4 x0 = *(const float4*)&x0p[j0];
    const float4 x1 = *(const float4*)&x1p[j0];
    const float4 kh = cw[15 - b], kl = cw[14 - b];
    const float ck[8] = {kl.x, kl.y, kl.z, kl.w, kh.x, kh.y, kh.z, kh.w};
    const float xs0[4] = {x0.x, x0.y, x0.z, x0.w};
    const float xs1[4] = {x1.x, x1.y, x1.z, x1.w};
#pragma unroll
    for (int s = 0; s < 4; ++s)
#pragma unroll
      for (int r = 0; r < 4; ++r) {
        const int c = 4 + r - s;
        a0[r] = fmaf(xs0[s], ck[c], a0[r]);
        a1[r] = fmaf(xs1[s], ck[c], a1[r]);
      }
  }
}

// V conv: 3 f16 dot2 convs; superblock = 8 j = 4 packed pairs (one uint4)
// pair-dword index: tt = r - 2p - 8sb + (NSB*8-2); stored at winq dword tt+2
template <int NSB>
__device__ __forceinline__ void vConv3(const unsigned* q0, const unsigned* q1,
                                       const unsigned* q2, int jgp,
                                       const float4* win, float (&A)[3][4]) {
#pragma unroll
  for (int sb = 0; sb < NSB; ++sb) {
    const int base = jgp + 4 * sb;
    const uint4 X0 = *(const uint4*)&q0[base];
    const uint4 X1 = *(const uint4*)&q1[base];
    const uint4 X2 = *(const uint4*)&q2[base];
    const unsigned xs0[4] = {X0.x, X0.y, X0.z, X0.w};
    const unsigned xs1[4] = {X1.x, X1.y, X1.z, X1.w};
    const unsigned xs2[4] = {X2.x, X2.y, X2.z, X2.w};
#pragma unroll
    for (int p = 0; p < 4; ++p)
#pragma unroll
      for (int r = 0; r < 4; ++r) {
        const int di = r - 2 * p - 8 * sb + (NSB * 8 - 2) + 2;  // compile-time
        const h2 c = bch2(__float_as_uint(wdw(win, di)));
        A[0][r] = fdot2(c, bch2(xs0[p]), A[0][r]);
        A[1][r] = fdot2(c, bch2(xs1[p]), A[1][r]);
        A[2][r] = fdot2(c, bch2(xs2[p]), A[2][r]);
      }
  }
}

// final-iter: 4 f16 product convs
template <int NSB>
__device__ __forceinline__ void vConv4(const unsigned (*q)[NPAD / 2], int jgp,
                                       const float4* win, float (&A)[4][4]) {
#pragma unroll
  for (int sb = 0; sb < NSB; ++sb) {
    const int base = jgp + 4 * sb;
    const uint4 X0 = *(const uint4*)&q[0][base];
    const uint4 X1 = *(const uint4*)&q[1][base];
    const uint4 X2 = *(const uint4*)&q[2][base];
    const uint4 X3 = *(const uint4*)&q[3][base];
    const unsigned xs0[4] = {X0.x, X0.y, X0.z, X0.w};
    const unsigned xs1[4] = {X1.x, X1.y, X1.z, X1.w};
    const unsigned xs2[4] = {X2.x, X2.y, X2.z, X2.w};
    const unsigned xs3[4] = {X3.x, X3.y, X3.z, X3.w};
#pragma unroll
    for (int p = 0; p < 4; ++p)
#pragma unroll
      for (int r = 0; r < 4; ++r) {
        const int di = r - 2 * p - 8 * sb + (NSB * 8 - 2) + 2;
        const h2 c = bch2(__float_as_uint(wdw(win, di)));
        A[0][r] = fdot2(c, bch2(xs0[p]), A[0][r]);
        A[1][r] = fdot2(c, bch2(xs1[p]), A[1][r]);
        A[2][r] = fdot2(c, bch2(xs2[p]), A[2][r]);
        A[3][r] = fdot2(c, bch2(xs3[p]), A[3][r]);
      }
  }
}

__global__ void __launch_bounds__(NTH, 2)
hf_kernel(const float* __restrict__ wfy0,
          const float* __restrict__ kin,
          const float* __restrict__ vnt,
          const float* __restrict__ uho_g,
          const float* __restrict__ delx_p,
          const float* __restrict__ pfac_p,
          const int*   __restrict__ iter_p,
          float* __restrict__ out)
{
  __shared__ Smem sm;
  const int t  = (int)threadIdx.x;
  const int wv = t >> 6;
  const int l  = t & 63;
  const int i0 = 4 * l;              // output quad owned by this lane
  const bool isK = (wv < 4);
  const int g  = isK ? wv : wv - 4;  // group 0..3
  const int jgK = KJCH * g;          // K chunks {60,60,60,60}
  const int jgV = 64 * g;            // V chunks {64,64,64,48}
  const int lenV = (g < 3) ? 64 : 48;
  const float delx = delx_p[0];
  const float pfac = pfac_p[0];
  const int itermax = iter_p[0];

  // ---- setup: Toeplitz coeff tables (kin fp32, Vint packed f16 pairs) ----
  for (int a = t; a < 512; a += NTH) {
    int d = a - 256;                 // d = i - j
    float vk = 0.f;
    if (d >= 0 && d < NXX)      vk = kin[(size_t)d * NXX];
    else if (d < 0 && -d < NXX) vk = kin[-d];
    sm.cK[a] = vk;
    float vh = 0.f, vl = 0.f;
    if (d >= 0 && d < NXX)      vh = vnt[(size_t)d * NXX];
    else if (d < 0 && -d < NXX) vh = vnt[-d];
    int d2 = d - 1;
    if (d2 >= 0 && d2 < NXX)      vl = vnt[(size_t)d2 * NXX];
    else if (d2 < 0 && -d2 < NXX) vl = vnt[-d2];
    sm.pkV[a] = pkh(vh, vl);         // (cV[a], cV[a-1])
  }
  if (t < NPAD) {
    float u  = (t < NXX) ? uho_g[t]        : 0.f;
    float a0 = (t < NXX) ? wfy0[2 * t]     : 0.f;
    float a1 = (t < NXX) ? wfy0[2 * t + 1] : 0.f;
    sm.uho[t] = u;
    sm.wfb[0][0][t] = a0; sm.wfb[0][1][t] = a1;
    sm.wfb[1][0][t] = 0.f; sm.wfb[1][1][t] = 0.f;
  }
  if (t < NPAD / 2) {                // initial packed p-arrays
    int j0 = 2 * t, j1 = 2 * t + 1;
    float w00 = (j0 < NXX) ? wfy0[2 * j0]     : 0.f;
    float w01 = (j0 < NXX) ? wfy0[2 * j0 + 1] : 0.f;
    float w10 = (j1 < NXX) ? wfy0[2 * j1]     : 0.f;
    float w11 = (j1 < NXX) ? wfy0[2 * j1 + 1] : 0.f;
    sm.xpk[0][t] = pkh(w00 * w00, w10 * w10);
    sm.xpk[1][t] = pkh(w00 * w01, w10 * w11);
    sm.xpk[2][t] = pkh(w01 * w01, w11 * w11);
  }
  __syncthreads();

  // ---- ONE quad-typed persistent window: float4 winq[17] (68 regs) ----
  // K-wave: R4-verbatim fp32 quads, qb = l - 15g + 49, winq[16] = 0.
  // V-wave: 17 uint4 loads of packed pairs from 4-aligned base
  //         ab = i0 - jgV - lenV + 256; dword di = tt + 2.
  float4 winq[17];
  if (isK) {
    const int qb = l - 15 * g + 49;
#pragma unroll
    for (int m = 0; m < 16; ++m) winq[m] = *(const float4*)&sm.cK[4 * (qb + m)];
    winq[16] = make_float4(0.f, 0.f, 0.f, 0.f);
  } else {
    const int ab = i0 - jgV - lenV + 256;   // multiple of 4
#pragma unroll
    for (int m = 0; m < 17; ++m) {
      const uint4 q = *(const uint4*)&sm.pkV[ab + 4 * m];
      winq[m] = make_float4(__uint_as_float(q.x), __uint_as_float(q.y),
                            __uint_as_float(q.z), __uint_as_float(q.w));
    }
  }

  int cur = 0;
  for (int it = 0; it < itermax; ++it) {
    const bool last = (it == itermax - 1);
    const float* wf0 = sm.wfb[cur][0];
    const float* wf1 = sm.wfb[cur][1];
    float* nw0 = sm.wfb[cur ^ 1][0];
    float* nw1 = sm.wfb[cur ^ 1][1];

    // ===== conv phase: K: kin@wf0, kin@wf1 (fp32); V: V@p00,p01,p11 (f16) ====
    if (isK) {
      float aK0[4] = {0, 0, 0, 0}, aK1[4] = {0, 0, 0, 0};
      kinConv(wf0, wf1, jgK, winq, aK0, aK1);
      *(float4*)&sm.part[g][0][i0] = make_float4(aK0[0], aK0[1], aK0[2], aK0[3]);
      *(float4*)&sm.part[g][1][i0] = make_float4(aK1[0], aK1[1], aK1[2], aK1[3]);
    } else {
      float aV[3][4] = {};
      if (g < 3) vConv3<8>(sm.xpk[0], sm.xpk[1], sm.xpk[2], jgV / 2, winq, aV);
      else       vConv3<6>(sm.xpk[0], sm.xpk[1], sm.xpk[2], jgV / 2, winq, aV);
#pragma unroll
      for (int c = 0; c < 3; ++c)
        *(float4*)&sm.part[g][2 + c][i0] =
            make_float4(aV[c][0], aV[c][1], aV[c][2], aV[c][3]);
    }
    __syncthreads();   // B1

    // ===== serial wave-0 vector phase: ONE batched reduction (R4) =====
    float w0[4], w1[4], Ut[4], wff0[4], wff1[4], new0[4], new1[4];
    float spe0 = 0.f, spe1 = 0.f, eho = 0.f;

    if (wv == 0) {
      const bool valid = (l < 60);   // rows i0..i0+3 < 240
      float k0[4]  = {0, 0, 0, 0}, k1[4]  = {0, 0, 0, 0};
      float v00[4] = {0, 0, 0, 0}, v01[4] = {0, 0, 0, 0}, v11[4] = {0, 0, 0, 0};
#pragma unroll
      for (int gg = 0; gg < 4; ++gg) {
        const float4 A0 = *(const float4*)&sm.part[gg][0][i0];
        const float4 A1 = *(const float4*)&sm.part[gg][1][i0];
        const float4 A2 = *(const float4*)&sm.part[gg][2][i0];
        const float4 A3 = *(const float4*)&sm.part[gg][3][i0];
        const float4 A4 = *(const float4*)&sm.part[gg][4][i0];
        k0[0]  += A0.x; k0[1]  += A0.y; k0[2]  += A0.z; k0[3]  += A0.w;
        k1[0]  += A1.x; k1[1]  += A1.y; k1[2]  += A1.z; k1[3]  += A1.w;
        v00[0] += A2.x; v00[1] += A2.y; v00[2] += A2.z; v00[3] += A2.w;
        v01[0] += A3.x; v01[1] += A3.y; v01[2] += A3.z; v01[3] += A3.w;
        v11[0] += A4.x; v11[1] += A4.y; v11[2] += A4.z; v11[3] += A4.w;
      }
      const float4 w0q = *(const float4*)&wf0[i0];
      const float4 w1q = *(const float4*)&wf1[i0];
      const float4 uq  = *(const float4*)&sm.uho[i0];
      w0[0] = w0q.x; w0[1] = w0q.y; w0[2] = w0q.z; w0[3] = w0q.w;
      w1[0] = w1q.x; w1[1] = w1q.y; w1[2] = w1q.z; w1[3] = w1q.w;
      const float uh[4] = {uq.x, uq.y, uq.z, uq.w};

      float wb0[4], wb1[4];
      float red[6] = {0, 0, 0, 0, 0, 0};  // s0, s1, c01, d01, a00, sw0
#pragma unroll
      for (int r = 0; r < 4; ++r) {
        Ut[r]   = delx * (v00[r] + v11[r]) + uh[r];          // Udir + U_HO
        wff0[r] = k0[r] - delx * (w0[r] * v00[r] + w1[r] * v01[r]) + Ut[r] * w0[r];
        wff1[r] = k1[r] - delx * (w0[r] * v01[r] + w1[r] * v11[r]) + Ut[r] * w1[r];
        wb0[r]  = w0[r] - pfac * wff0[r];
        wb1[r]  = w1[r] - pfac * wff1[r];
        if (!valid) { wb0[r] = 0.f; wb1[r] = 0.f; }          // mask pad rows
        red[0] += wb0[r] * wb0[r];
        red[1] += wb1[r] * wb1[r];
        red[2] += wb0[r] * wb1[r];
        red[3] += w0[r]  * wb1[r];
        red[4] += wb0[r] * w0[r];
        red[5] += w0[r]  * w0[r];
      }
      waveSumDppN<6>(red);
      const float rdelx = 1.f / delx;
      const float inv0 = 1.f / sqrtf(red[0] * delx);   // 1/||wb0||
      const float inv1 = 1.f / sqrtf(red[1] * delx);   // 1/||wb1||
      const float dB = delx * inv1 * (0.4f * red[2] * inv0 + 0.6f * red[3]);
      const float e0 = 0.16f * rdelx + 0.48f * red[4] * inv0 + 0.36f * red[5];
      const float sB = rdelx - dB * dB * (2.f * rdelx - e0);
      const float invB = 1.f / (sB * delx);
#pragma unroll
      for (int r = 0; r < 4; ++r) {
        const float wfA  = wb0[r] * inv0;
        const float wfBp = wb1[r] * inv1;
        new0[r] = 0.4f * wfA + 0.6f * w0[r];           // n2A == 1 identity
        const float wfB2 = wfBp - new0[r] * dB;
        new1[r] = 0.4f * wfB2 * invB + 0.6f * w1[r];
      }
      *(float4*)&nw0[i0] = make_float4(new0[0], new0[1], new0[2], new0[3]);
      *(float4*)&nw1[i0] = make_float4(new1[0], new1[1], new1[2], new1[3]);
      // packed f16 p-arrays for next iteration's V convs (pads stay 0)
      *(uint2*)&sm.xpk[0][2 * l] = make_uint2(
          pkh(new0[0] * new0[0], new0[1] * new0[1]),
          pkh(new0[2] * new0[2], new0[3] * new0[3]));
      *(uint2*)&sm.xpk[1][2 * l] = make_uint2(
          pkh(new0[0] * new1[0], new0[1] * new1[1]),
          pkh(new0[2] * new1[2], new0[3] * new1[3]));
      *(uint2*)&sm.xpk[2][2 * l] = make_uint2(
          pkh(new1[0] * new1[0], new1[1] * new1[1]),
          pkh(new1[2] * new1[2], new1[3] * new1[3]));

      if (last) {
        float er[3] = {0, 0, 0};                       // spe0, spe1, eho
#pragma unroll
        for (int r = 0; r < 4; ++r) {
          er[0] += w0[r] * wff0[r];                    // w0=0 on pads
          er[1] += w1[r] * wff1[r];
          er[2] += (w0[r] * w0[r] + w1[r] * w1[r]) * uh[r];
        }
        waveSumDppN<3>(er);
        spe0 = er[0] * delx; spe1 = er[1] * delx; eho = er[2] * delx * 0.5f;
      }
    }
    __syncthreads();   // B2 — next conv may read nw*/xpk safely

    // ===== final iteration: ekin/epot =====
    if (last) {
      // pack products wf_m * new_n as f16 pairs (threads 0..127)
      if (t < NPAD / 2) {
        const float2 o0 = *(const float2*)&wf0[2 * t];
        const float2 o1 = *(const float2*)&wf1[2 * t];
        const float2 n0 = *(const float2*)&nw0[2 * t];
        const float2 n1 = *(const float2*)&nw1[2 * t];
        sm.xprk[0][t] = pkh(o0.x * n0.x, o0.y * n0.y);
        sm.xprk[1][t] = pkh(o1.x * n0.x, o1.y * n0.y);
        sm.xprk[2][t] = pkh(o0.x * n1.x, o0.y * n1.y);
        sm.xprk[3][t] = pkh(o1.x * n1.x, o1.y * n1.y);
      }
      __syncthreads();  // B3 (last iter only)

      if (isK) {
        float bA0[4] = {0, 0, 0, 0}, bA1[4] = {0, 0, 0, 0};
        kinConv(nw0, nw1, jgK, winq, bA0, bA1);
        *(float4*)&sm.part[g][0][i0] = make_float4(bA0[0], bA0[1], bA0[2], bA0[3]);
        *(float4*)&sm.part[g][1][i0] = make_float4(bA1[0], bA1[1], bA1[2], bA1[3]);
      } else {
        float bV[4][4] = {};
        if (g < 3) vConv4<8>(sm.xprk, jgV / 2, winq, bV);
        else       vConv4<6>(sm.xprk, jgV / 2, winq, bV);
#pragma unroll
        for (int c2 = 0; c2 < 4; ++c2)
          *(float4*)&sm.part[g][2 + c2][i0] =
              make_float4(bV[c2][0], bV[c2][1], bV[c2][2], bV[c2][3]);
      }
      __syncthreads();  // B4

      if (wv == 0) {
        float rd[6][4] = {};
#pragma unroll
        for (int gg = 0; gg < 4; ++gg)
#pragma unroll
          for (int c = 0; c < 6; ++c) {
            const float4 A = *(const float4*)&sm.part[gg][c][i0];
            rd[c][0] += A.x; rd[c][1] += A.y; rd[c][2] += A.z; rd[c][3] += A.w;
          }
        float er[2] = {0, 0};                          // ekin, epot integrands
#pragma unroll
        for (int r = 0; r < 4; ++r) {
          // pads contribute 0: w0=w1=new0=new1=0 there
          const float um0 = -delx * (w0[r] * rd[2][r] + w1[r] * rd[3][r]) + Ut[r] * new0[r];
          const float um1 = -delx * (w0[r] * rd[4][r] + w1[r] * rd[5][r]) + Ut[r] * new1[r];
          er[0] += new0[r] * rd[0][r] + new1[r] * rd[1][r];
          er[1] += new0[r] * um0 + new1[r] * um1;
        }
        waveSumDppN<2>(er);
        const float ekin = er[0] * delx, epot = er[1] * delx;
        if (l == 0) {
          const float esum    = spe0 + spe1;
          const float enerhfp = 0.5f * (esum + ekin) + eho;
          const float epot0hf = epot - 2.f * eho;
          const float enerhf  = esum - 0.5f * epot0hf;
          out[0] = enerhf; out[1] = enerhfp; out[2] = ekin;
          out[3] = eho;    out[4] = epot0hf; out[5] = esum;
        }
      }
    }
    cur ^= 1;
  }
}

extern "C" void kernel_launch(void* const* d_in, const int* in_sizes, int n_in,
                              void* d_out, int out_size, void* d_ws, size_t ws_size,
                              hipStream_t stream) {
  const float* wfy0 = (const float*)d_in[0];
  const float* kin  = (const float*)d_in[1];
  const float* vnt  = (const float*)d_in[2];
  const float* uho  = (const float*)d_in[3];
  const float* delx = (const float*)d_in[4];
  const float* pfac = (const float*)d_in[5];
  const int*   itm  = (const int*)d_in[6];
  hipLaunchKernelGGL(hf_kernel, dim3(1), dim3(NTH), 0, stream,
                     wfy0, kin, vnt, uho, delx, pfac, itm, (float*)d_out);
}